// Round 10
// baseline (435.153 us; speedup 1.0000x reference)
//
#include <hip/hip_runtime.h>
#include <math.h>

// Pipeline (d_out doubles as scratch for the A hi/lo split = exactly 134.2MB):
//   k0 split_a:   A fp32 [65536,512] -> Ah,Al fp16 (row-major) in d_out
//   k1 gemm:      qkv[65536,1536] = (Ah+Al) @ fp16(W)^T + bias   (in d_ws)
//                 A staged via global_load_lds (no VALU), W reg-staged+cvt,
//                 counted vmcnt(4) + raw barrier (loads stay in flight)
//   k2 scramble:  qkv -> out (overwrites d_out; verified round 1)

typedef _Float16 half8 __attribute__((ext_vector_type(8)));
typedef __fp16 fp16x2 __attribute__((ext_vector_type(2)));
typedef float f32x4 __attribute__((ext_vector_type(4)));

__device__ __forceinline__ half8 pk8(const float4 x, const float4 y) {
    fp16x2 a = __builtin_amdgcn_cvt_pkrtz(x.x, x.y);
    fp16x2 b = __builtin_amdgcn_cvt_pkrtz(x.z, x.w);
    fp16x2 c = __builtin_amdgcn_cvt_pkrtz(y.x, y.y);
    fp16x2 d = __builtin_amdgcn_cvt_pkrtz(y.z, y.w);
    half8 r;
    r[0] = (_Float16)a[0]; r[1] = (_Float16)a[1];
    r[2] = (_Float16)b[0]; r[3] = (_Float16)b[1];
    r[4] = (_Float16)c[0]; r[5] = (_Float16)c[1];
    r[6] = (_Float16)d[0]; r[7] = (_Float16)d[1];
    return r;
}
__device__ __forceinline__ void pk8_hilo(const float4 x, const float4 y,
                                         half8& h, half8& l) {
    h = pk8(x, y);
    float4 rx, ry;
    rx.x = x.x - (float)h[0]; rx.y = x.y - (float)h[1];
    rx.z = x.z - (float)h[2]; rx.w = x.w - (float)h[3];
    ry.x = y.x - (float)h[4]; ry.y = y.y - (float)h[5];
    ry.z = y.z - (float)h[6]; ry.w = y.w - (float)h[7];
    l = pk8(rx, ry);
}

__device__ __forceinline__ void gload_lds16(const void* g, void* l) {
    __builtin_amdgcn_global_load_lds(
        (const __attribute__((address_space(1))) unsigned int*)g,
        (__attribute__((address_space(3))) unsigned int*)l, 16, 0, 0);
}

// ---------------------------------------------------------------------------
// k0: streaming split A -> fp16 hi/lo (row-major, same indexing as A)
// ---------------------------------------------------------------------------
__global__ __launch_bounds__(256) void split_a(
    const float* __restrict__ A,
    _Float16* __restrict__ hi, _Float16* __restrict__ lo)
{
    const size_t i = (size_t)blockIdx.x * 256 + threadIdx.x;   // 8 floats each
    const float4 x = *reinterpret_cast<const float4*>(A + i * 8);
    const float4 y = *reinterpret_cast<const float4*>(A + i * 8 + 4);
    half8 h, l;
    pk8_hilo(x, y, h, l);
    *reinterpret_cast<half8*>(hi + i * 8) = h;
    *reinterpret_cast<half8*>(lo + i * 8) = l;
}

// ---------------------------------------------------------------------------
// k1: C[65536,1536] = A @ W^T + bias.  BM=BN=128, BK=32, 4 waves (2x2).
// LDS/buffer (halfword offsets): Ah [0,4096) Al [4096,8192) Wh [8192,12288).
// Swizzle: 16B chunk c of row r at phys c ^ ((r>>1)&3) — r8-proven (0 conf).
// A: global_load_lds, XOR applied on the per-lane GLOBAL source (rule 21).
// ---------------------------------------------------------------------------
__global__ __launch_bounds__(256, 3) void gemm_qkv_glds(
    const _Float16* __restrict__ Ah, const _Float16* __restrict__ Al,
    const float* __restrict__ W, const float* __restrict__ bias,
    float* __restrict__ C)
{
    __shared__ __align__(16) _Float16 lds[24576];   // 2 x 24 KB

    const int lin = blockIdx.x;                      // 6144 blocks, %8==0
    const int swz = (lin & 7) * 768 + (lin >> 3);
    const int nt = swz % 12, mt = swz / 12;
    const int row0 = mt * 128, col0 = nt * 128;

    const int tid = threadIdx.x, wid = tid >> 6, lane = tid & 63;
    const int wm = wid >> 1, wn = wid & 1, l15 = lane & 15, kq = lane >> 4;

    // A staging: wave wid owns 1KB segments s0, s0+1 of the 8KB hi (and lo) tile.
    // Lane j writes LDS bytes seg*1024 + j*16 (hardware-linear), i.e. tile slot
    // (row = seg*16 + j>>2, phys chunk = j&3); source must hold logical chunk
    // (j&3) ^ ((row>>1)&3).
    const int s0  = wid * 2;
    const int rA0 = s0 * 16 + (lane >> 2);
    const int rA1 = rA0 + 16;
    const int c0  = (lane & 3) ^ ((rA0 >> 1) & 3);
    const int c1  = (lane & 3) ^ ((rA1 >> 1) & 3);
    const _Float16* gh0 = Ah + (size_t)(row0 + rA0) * 512 + c0 * 8;
    const _Float16* gh1 = Ah + (size_t)(row0 + rA1) * 512 + c1 * 8;
    const _Float16* gl0 = Al + (size_t)(row0 + rA0) * 512 + c0 * 8;
    const _Float16* gl1 = Al + (size_t)(row0 + rA1) * 512 + c1 * 8;

    // W staging (reg + cvt, r8-proven): thread covers row rw, k kh..kh+15
    const int rw = tid >> 1, khw = (tid & 1) * 16;
    const float* Wg = W + (size_t)(col0 + rw) * 512 + khw;
    const int wsw = (rw >> 1) & 3;
    const int wcA = (((khw >> 3) + 0) ^ wsw) * 8;
    const int wcB = (((khw >> 3) + 1) ^ wsw) * 8;

    f32x4 acc[4][4];
#pragma unroll
    for (int i = 0; i < 4; ++i)
#pragma unroll
        for (int j = 0; j < 4; ++j) acc[i][j] = (f32x4)0.f;

    // ---- prologue: k-tile 0 into buf0; W regs advance to k-tile 1 ----
    float4 w0 = *reinterpret_cast<const float4*>(Wg + 0);
    float4 w1 = *reinterpret_cast<const float4*>(Wg + 4);
    float4 w2 = *reinterpret_cast<const float4*>(Wg + 8);
    float4 w3 = *reinterpret_cast<const float4*>(Wg + 12);
    {
        _Float16* b0 = lds;
        gload_lds16(gh0, b0 + s0 * 512);
        gload_lds16(gh1, b0 + (s0 + 1) * 512);
        gload_lds16(gl0, b0 + 4096 + s0 * 512);
        gload_lds16(gl1, b0 + 4096 + (s0 + 1) * 512);
        const half8 wv0 = pk8(w0, w1);
        const half8 wv1 = pk8(w2, w3);
        *reinterpret_cast<half8*>(b0 + 8192 + rw * 32 + wcA) = wv0;
        *reinterpret_cast<half8*>(b0 + 8192 + rw * 32 + wcB) = wv1;
    }
    w0 = *reinterpret_cast<const float4*>(Wg + 32);
    w1 = *reinterpret_cast<const float4*>(Wg + 36);
    w2 = *reinterpret_cast<const float4*>(Wg + 40);
    w3 = *reinterpret_cast<const float4*>(Wg + 44);
    asm volatile("s_waitcnt vmcnt(4) lgkmcnt(0)" ::: "memory");
    __builtin_amdgcn_sched_barrier(0);
    __builtin_amdgcn_s_barrier();
    __builtin_amdgcn_sched_barrier(0);

#define FRAG_MFMA(BC)                                                          \
    do {                                                                       \
        half8 ah[4], al[4];                                                    \
        _Pragma("unroll")                                                      \
        for (int mf = 0; mf < 4; ++mf) {                                       \
            const int r  = wm * 64 + mf * 16 + l15;                            \
            const int ph = (kq ^ ((r >> 1) & 3)) * 8;                          \
            ah[mf] = *reinterpret_cast<const half8*>((BC) + r * 32 + ph);      \
            al[mf] = *reinterpret_cast<const half8*>((BC) + 4096 + r * 32 + ph);\
        }                                                                      \
        _Pragma("unroll")                                                      \
        for (int nf = 0; nf < 4; ++nf) {                                       \
            const int rb = wn * 64 + nf * 16 + l15;                            \
            const int ph = (kq ^ ((rb >> 1) & 3)) * 8;                         \
            const half8 wv =                                                   \
                *reinterpret_cast<const half8*>((BC) + 8192 + rb * 32 + ph);   \
            _Pragma("unroll")                                                  \
            for (int mf = 0; mf < 4; ++mf) {                                   \
                acc[mf][nf] = __builtin_amdgcn_mfma_f32_16x16x32_f16(          \
                    ah[mf], wv, acc[mf][nf], 0, 0, 0);                         \
                acc[mf][nf] = __builtin_amdgcn_mfma_f32_16x16x32_f16(          \
                    al[mf], wv, acc[mf][nf], 0, 0, 0);                         \
            }                                                                  \
        }                                                                      \
    } while (0)

#pragma unroll 1
    for (int t = 0; t < 15; ++t) {
        const int cur = t & 1;
        const _Float16* bc = lds + cur * 12288;
        _Float16* bn = lds + (cur ^ 1) * 12288;
        const int kbN = (t + 1) * 32;

        // 1. issue A glds for k-tile t+1 (whole step to land)
        gload_lds16(gh0 + kbN, bn + s0 * 512);
        gload_lds16(gh1 + kbN, bn + (s0 + 1) * 512);
        gload_lds16(gl0 + kbN, bn + 4096 + s0 * 512);
        gload_lds16(gl1 + kbN, bn + 4096 + (s0 + 1) * 512);

        // 2. compute current tile
        FRAG_MFMA(bc);

        // 3. cvt W (regs hold k-tile t+1) -> bn
        {
            const half8 wv0 = pk8(w0, w1);
            const half8 wv1 = pk8(w2, w3);
            *reinterpret_cast<half8*>(bn + 8192 + rw * 32 + wcA) = wv0;
            *reinterpret_cast<half8*>(bn + 8192 + rw * 32 + wcB) = wv1;
        }
        // 4. W regs <- k-tile t+2. Needed through t=13 (loads k-tile 15 at
        //    offset 480). t=14's load is dead -> clamp to 0. (r9 bug: clamp
        //    at t<13 made t=13 reload k-tile 0 -> last K-tile used wrong W.)
        {
            const int kb2 = (t < 14) ? (t + 2) * 32 : 0;
            w0 = *reinterpret_cast<const float4*>(Wg + kb2 + 0);
            w1 = *reinterpret_cast<const float4*>(Wg + kb2 + 4);
            w2 = *reinterpret_cast<const float4*>(Wg + kb2 + 8);
            w3 = *reinterpret_cast<const float4*>(Wg + kb2 + 12);
        }
        // 5. counted drain: 4 glds must land; 4 W loads stay in flight
        asm volatile("s_waitcnt vmcnt(4) lgkmcnt(0)" ::: "memory");
        __builtin_amdgcn_sched_barrier(0);
        __builtin_amdgcn_s_barrier();
        __builtin_amdgcn_sched_barrier(0);
    }
    // t = 15: compute-only (buf1)
    FRAG_MFMA(lds + 12288);
#undef FRAG_MFMA

    // epilogue: C/D layout col = lane&15, row = (lane>>4)*4 + j (r8-verified)
    float bv[4];
#pragma unroll
    for (int nf = 0; nf < 4; ++nf)
        bv[nf] = bias[col0 + wn * 64 + nf * 16 + l15];

#pragma unroll
    for (int mf = 0; mf < 4; ++mf)
#pragma unroll
        for (int nf = 0; nf < 4; ++nf) {
            const int c = col0 + wn * 64 + nf * 16 + l15;
#pragma unroll
            for (int j = 0; j < 4; ++j) {
                const int r = row0 + wm * 64 + mf * 16 + kq * 4 + j;
                C[(size_t)r * 1536 + c] = acc[mf][nf][j] + bv[nf];
            }
        }
}

// ---------------------------------------------------------------------------
// k2: scrambled elementwise softmax (verified round 1, unchanged)
// ---------------------------------------------------------------------------
__global__ __launch_bounds__(256) void attn_scramble(
    const float* __restrict__ qkv, float* __restrict__ out)
{
    __shared__ float Ks[64][65];
    const int bid = blockIdx.x;
    const int hw6 = bid & 63;
    const int n   = (bid >> 6) & 7;
    const int b   = bid >> 9;
    const int kn  = (n + 7) & 7;
    const int t   = threadIdx.x;
    {
        const int hwlo = t & 63;
        const int d0   = t >> 6;
#pragma unroll
        for (int s = 0; s < 16; ++s) {
            const int dp = s * 4 + d0;
            Ks[dp][hwlo] =
                qkv[(size_t)(b * 4096 + dp * 64 + hw6) * 1536 + 512 + kn * 64 + hwlo];
        }
    }
    __syncthreads();
    const int row = t >> 2;
    const int tl  = t & 3;
    const size_t rbase = (size_t)(b * 4096 + hw6 * 64 + row) * 1536;
    float s[16];
    {
        const float* qp = qkv + rbase + n * 64 + tl * 16;
        float q[16];
#pragma unroll
        for (int u = 0; u < 4; ++u)
            *reinterpret_cast<float4*>(&q[u * 4]) =
                *reinterpret_cast<const float4*>(qp + u * 4);
        float m = -1e30f;
#pragma unroll
        for (int u = 0; u < 16; ++u) {
            s[u] = 0.125f * q[u] * Ks[tl * 16 + u][row];
            m = fmaxf(m, s[u]);
        }
        m = fmaxf(m, __shfl_xor(m, 1));
        m = fmaxf(m, __shfl_xor(m, 2));
        float sum = 0.f;
#pragma unroll
        for (int u = 0; u < 16; ++u) {
            s[u] = __expf(s[u] - m);
            sum += s[u];
        }
        sum += __shfl_xor(sum, 1);
        sum += __shfl_xor(sum, 2);
        const float inv = 1.0f / sum;
#pragma unroll
        for (int u = 0; u < 16; ++u) s[u] *= inv;
    }
    const float* vp = qkv + rbase + 1024 + kn * 64 + tl * 16;
    const int vb = b >> 3, fr = b & 7;
    float* op = out +
        ((size_t)(((vb * 8 + (hw6 >> 3)) * 64 + ((hw6 & 7) * 8 + (row >> 3))) * 64 +
                  ((row & 7) * 8 + n)) * 512) + fr * 64 + tl * 16;
#pragma unroll
    for (int u = 0; u < 4; ++u) {
        const float4 v = *reinterpret_cast<const float4*>(vp + u * 4);
        float4 o;
        o.x = s[u * 4 + 0] * v.x;
        o.y = s[u * 4 + 1] * v.y;
        o.z = s[u * 4 + 2] * v.z;
        o.w = s[u * 4 + 3] * v.w;
        *reinterpret_cast<float4*>(op + u * 4) = o;
    }
}

// ---------------------------------------------------------------------------
extern "C" void kernel_launch(void* const* d_in, const int* in_sizes, int n_in,
                              void* d_out, int out_size, void* d_ws, size_t ws_size,
                              hipStream_t stream) {
    const float* hs = (const float*)d_in[0];  // [65536,512]
    const float* w  = (const float*)d_in[1];  // [1536,512]
    const float* bq = (const float*)d_in[2];  // [1536]
    float* out = (float*)d_out;
    float* qkv = (float*)d_ws;                // 402,653,184 B (fits: r1+ ran)

    // d_out as scratch for the A split: Ah | Al, 67,108,864 B each (exact fit)
    _Float16* Asp_h = (_Float16*)d_out;
    _Float16* Asp_l = Asp_h + 33554432;       // 65536*512

    split_a<<<16384, 256, 0, stream>>>(hs, Asp_h, Asp_l);
    gemm_qkv_glds<<<6144, 256, 0, stream>>>(Asp_h, Asp_l, w, bq, qkv);
    attn_scramble<<<8192, 256, 0, stream>>>(qkv, out);
}